// Round 14
// baseline (196.023 us; speedup 1.0000x reference)
//
#include <hip/hip_runtime.h>
#include <hip/hip_bf16.h>

#define TOKENS 8192
#define IN_F   4096
#define OUT_F  4096

// GEMM geometry: 256x256 tile, K_STEP=128 (4 x K=32 MFMA steps), 8 waves
#define BM 256
#define BN 256
#define KSTEP 128
#define NT (IN_F / KSTEP)   // 32 K-tiles

typedef int   i32x4   __attribute__((ext_vector_type(4)));
typedef int   i32x16  __attribute__((ext_vector_type(16)));

#define BARRIER() asm volatile("s_barrier" ::: "memory")
#define VMCNT4()  asm volatile("s_waitcnt vmcnt(4)" ::: "memory")
#define VMCNT2()  asm volatile("s_waitcnt vmcnt(2)" ::: "memory")
#define VMCNT0()  asm volatile("s_waitcnt vmcnt(0)" ::: "memory")

#define MFMA32(a, b, c) __builtin_amdgcn_mfma_i32_32x32x32_i8((a), (b), (c), 0, 0, 0)

__device__ __forceinline__ void gload_lds16(const void* g, void* l) {
  __builtin_amdgcn_global_load_lds(
      (const __attribute__((address_space(1))) void*)g,
      (__attribute__((address_space(3))) void*)l, 16, 0, 0);
}

__device__ __forceinline__ float blockmax256(float m, float* red) {
#pragma unroll
  for (int off = 32; off; off >>= 1)
    m = fmaxf(m, __shfl_xor(m, off, 64));
  if ((threadIdx.x & 63) == 0) red[threadIdx.x >> 6] = m;
  __syncthreads();
  return fmaxf(fmaxf(red[0], red[1]), fmaxf(red[2], red[3]));
}

__device__ __forceinline__ int pack4(const float* v, float inv) {
  unsigned w = 0;
#pragma unroll
  for (int b = 0; b < 4; ++b) {
    int q = __float2int_rn(fmaxf(fminf(v[b] * inv, 127.f), -127.f));
    w |= ((unsigned)(unsigned char)(signed char)q) << (8 * b);
  }
  return (int)w;
}

// ---------------------------------------------------------------------------
// Kernel 1: W_full = dequant_int4 + CSR ortho -> per-row i8 quant + scale.
// ---------------------------------------------------------------------------
__global__ __launch_bounds__(256) void prep_w_i8(
    const int* __restrict__ bw, const float* __restrict__ scales,
    const float* __restrict__ vals, const int* __restrict__ cols,
    const int* __restrict__ rptr, signed char* __restrict__ Wq,
    float* __restrict__ sw) {
  __shared__ float row[IN_F];
  __shared__ float red[4];
  const int n = blockIdx.x;
  const int tid = threadIdx.x;
  const float s = scales[n];
  const int* bwr = bw + (size_t)n * (IN_F / 2);
#pragma unroll
  for (int it = 0; it < (IN_F / 2) / 256; ++it) {
    int j = it * 256 + tid;
    int p = bwr[j];
    int lo = p & 15;        lo = (lo >= 8) ? lo - 16 : lo;
    int hi = (p >> 4) & 15; hi = (hi >= 8) ? hi - 16 : hi;
    row[2 * j]     = (float)lo * s;
    row[2 * j + 1] = (float)hi * s;
  }
  __syncthreads();
  const int b = rptr[n], e = rptr[n + 1];
  for (int t = b + tid; t < e; t += 256)
    atomicAdd(&row[cols[t]], vals[t]);
  __syncthreads();
  float m = 0.f;
#pragma unroll
  for (int it = 0; it < IN_F / 256; ++it)
    m = fmaxf(m, fabsf(row[it * 256 + tid]));
  const float mm  = fmaxf(blockmax256(m, red), 1e-30f);
  const float inv = 127.f / mm;
  int4 w;
  w.x = pack4(&row[tid * 16 + 0],  inv);
  w.y = pack4(&row[tid * 16 + 4],  inv);
  w.z = pack4(&row[tid * 16 + 8],  inv);
  w.w = pack4(&row[tid * 16 + 12], inv);
  *(int4*)(Wq + (size_t)n * IN_F + tid * 16) = w;
  if (tid == 0) sw[n] = mm / 127.f;
}

// ---------------------------------------------------------------------------
// Kernel 2: X fp32 -> per-token i8 quant + scale.
// ---------------------------------------------------------------------------
__global__ __launch_bounds__(256) void cvt_x_i8(
    const float4* __restrict__ x, int* __restrict__ xq,
    float* __restrict__ sx) {
  __shared__ float red[4];
  const int tok = blockIdx.x;
  const int tid = threadIdx.x;
  const float4* xr = x + (size_t)tok * (IN_F / 4);
  float4 v[4];
  float m = 0.f;
#pragma unroll
  for (int j = 0; j < 4; ++j) {
    v[j] = xr[j * 256 + tid];
    m = fmaxf(m, fmaxf(fmaxf(fabsf(v[j].x), fabsf(v[j].y)),
                       fmaxf(fabsf(v[j].z), fabsf(v[j].w))));
  }
  const float mm  = fmaxf(blockmax256(m, red), 1e-30f);
  const float inv = 127.f / mm;
  int* xo = xq + (size_t)tok * (IN_F / 4);
#pragma unroll
  for (int j = 0; j < 4; ++j) {
    float vv[4] = {v[j].x, v[j].y, v[j].z, v[j].w};
    xo[j * 256 + tid] = pack4(vv, inv);
  }
  if (tid == 0) sx[tok] = mm / 127.f;
}

// ---------------------------------------------------------------------------
// Kernel 3: i8 GEMM — R9 sync skeleton (verified 129.7us) with
// mfma_i32_32x32x32_i8 (4404 vs 3944 TOPS; half the MFMA instructions).
//
// LDS image identical to R9 (per 256x128 tile = 32KB, two 16KB halves):
//   linear(r,kb) = (r>>4)*1024 + (r&15)*64 + kb ; stored at linear ^
//   ((linear>>9)&1)<<5. Staging macros byte-identical to R9.
//
// Wave tile 128x64 = 4(M) x 2(N) frags of 32x32, acc i32x16 each (128 reg).
// A-frag(f, kstep s): row = wr*128+f*32+(lane&31), k = s*32+(lane>>5)*16+e
//   -> LDS addr = rd{s&1} + (s>>1)*16384 + (wr*8+f*2)*1024   (+32768 for B)
// where rd0 = lds + (lo ^ x), rd1 = lds + ((lo+32) ^ x),
//   lo = ((lane>>4)&1)*1024 + (lane&15)*64 + (lane>>5)*16, x = bit9(lo)<<5
// (bit9 of the linear address depends only on lane -> XOR folds into the
//  precomputed base; +32 must be added BEFORE the XOR, hence two bases).
//
// 4 phases per tile, rotation s0..s3: phase p MFMAs frags(s=p), ds_reads
// frags(s=p+1), stages unit p of tile t+1; vmcnt(2)+barrier at P2/P4
// entries exactly as R9 (U1..U4 issue order preserved).
// ---------------------------------------------------------------------------
__global__ __launch_bounds__(512, 2) void gemm_i8(
    const unsigned char* __restrict__ A,   // [TOKENS][IN_F] i8
    const unsigned char* __restrict__ B,   // [OUT_F][IN_F] i8
    const float* __restrict__ sx,          // [TOKENS]
    const float* __restrict__ sw,          // [OUT_F]
    float* __restrict__ C) {               // [TOKENS][OUT_F] f32
  __shared__ __align__(16) char lds[131072];  // 2 buf x (A 32K + B 32K)

  const int nbn = OUT_F / BN;                  // 16
  const int cpx = ((TOKENS / BM) * nbn) >> 3;  // 64
  const int bid = blockIdx.x;
  const int swz = (bid & 7) * cpx + (bid >> 3);
  const int tm = swz / nbn, tn = swz % nbn;
  const long m0 = (long)tm * BM;
  const long n0 = (long)tn * BN;

  const int tid  = threadIdx.x;
  const int lane = tid & 63;
  const int wid  = tid >> 6;                // 0..7
  const int wr   = wid >> 2;                // 0..1 (M)
  const int wc   = wid & 3;                 // 0..3 (N)

  // ---- staging: linear LDS byte p -> logical (row, k-byte) (inverse swz)
  const int p0 = tid * 16;
  const int p1 = p0 + 8192;
  const int lin0 = p0 ^ (((p0 >> 9) & 1) << 5);
  const int lin1 = p1 ^ (((p1 >> 9) & 1) << 5);
  const int r0  = (((p0 >> 10) & 15) << 4) | ((lin0 >> 6) & 15);
  const int r1  = (((p1 >> 10) & 15) << 4) | ((lin1 >> 6) & 15);
  const int kb0 = lin0 & 63;
  const int kb1 = lin1 & 63;

  const unsigned char* Abase = A + m0 * IN_F;
  const unsigned char* Bbase = B + n0 * IN_F;

  // ---- reader lane bases (32x32 fragment pattern, swizzle folded in)
  const int lo = ((lane >> 4) & 1) * 1024 + (lane & 15) * 64 + (lane >> 5) * 16;
  const int xr_ = ((lo >> 9) & 1) << 5;          // bit9 is lane-only
  const char* rd0 = lds + (lo ^ xr_);            // k-lo 16B chunk of a step
  const char* rd1 = lds + ((lo + 32) ^ xr_);     // k-hi (s&1=1): +32 pre-XOR

#define STAGE_A(nb, kt, h)                                                     \
  do {                                                                         \
    gload_lds16(Abase + (size_t)r0 * IN_F + (kt) * 128 + (h) * 64 + kb0,       \
                lds + (nb) * 65536 + (h) * 16384 + p0);                        \
    gload_lds16(Abase + (size_t)r1 * IN_F + (kt) * 128 + (h) * 64 + kb1,       \
                lds + (nb) * 65536 + (h) * 16384 + p1);                        \
  } while (0)
#define STAGE_B(nb, kt, h)                                                     \
  do {                                                                         \
    gload_lds16(Bbase + (size_t)r0 * IN_F + (kt) * 128 + (h) * 64 + kb0,       \
                lds + (nb) * 65536 + 32768 + (h) * 16384 + p0);                \
    gload_lds16(Bbase + (size_t)r1 * IN_F + (kt) * 128 + (h) * 64 + kb1,       \
                lds + (nb) * 65536 + 32768 + (h) * 16384 + p1);                \
  } while (0)

// frag loads: s = k-step 0..3 (half = s>>1, parity picks rd0/rd1 base)
#define LD_A(dst, base, boff, s)                                               \
  do {                                                                         \
    _Pragma("unroll")                                                          \
    for (int f = 0; f < 4; ++f)                                                \
      dst[f] = *(const i32x4*)((base) + (boff) + ((s) >> 1) * 16384 +          \
                               (wr * 8 + f * 2) * 1024);                       \
  } while (0)
#define LD_B(dst, base, boff, s)                                               \
  do {                                                                         \
    _Pragma("unroll")                                                          \
    for (int g = 0; g < 2; ++g)                                                \
      dst[g] = *(const i32x4*)((base) + (boff) + 32768 + ((s) >> 1) * 16384 +  \
                               (wc * 4 + g * 2) * 1024);                       \
  } while (0)
#define MFMA_CLUSTER(av, bv)                                                   \
  do {                                                                         \
    _Pragma("unroll")                                                          \
    for (int f = 0; f < 4; ++f)                                                \
      _Pragma("unroll")                                                        \
      for (int g = 0; g < 2; ++g)                                              \
        acc[f][g] = MFMA32(av[f], bv[g], acc[f][g]);                           \
  } while (0)

  i32x16 acc[4][2];
#pragma unroll
  for (int f = 0; f < 4; ++f)
#pragma unroll
    for (int g = 0; g < 2; ++g) acc[f][g] = (i32x16)0;

  // fragment register sets (named, statically indexed — rule #20)
  i32x4 av1[4], av2[4], av3[4], av4[4], bv1[2], bv2[2], bv3[2], bv4[2];

  // ---- prologue: stage tile 0 into buf 0 (U1..U4); preload s0 frags
  STAGE_A(0, 0, 0);   // U1
  STAGE_B(0, 0, 0);   // U2
  STAGE_A(0, 0, 1);   // U3
  STAGE_B(0, 0, 1);   // U4
  VMCNT4();           // U1,U2 done -> h0 of tile 0 resident (per-wave)
  BARRIER();
  LD_A(av1, rd0, 0, 0);
  LD_B(bv1, rd0, 0, 0);

  for (int t = 0; t < NT; ++t) {
    const int b  = t & 1;
    const int nb = b ^ 1;
    const int boff  = b * 65536;
    const int nboff = nb * 65536;
    const bool pf = (t + 1 < NT);

    // ===== P1: MFMA s0 | ds_read s1 | stage U1(t+1) = A-h0
    BARRIER();
    __builtin_amdgcn_s_setprio(1);
    if (pf) STAGE_A(nb, t + 1, 0);
    LD_A(av2, rd1, boff, 1);
    LD_B(bv2, rd1, boff, 1);
    MFMA_CLUSTER(av1, bv1);
    __builtin_amdgcn_s_setprio(0);

    // ===== P2: MFMA s1 | ds_read s2 | stage U2(t+1) = B-h0
    if (pf) { VMCNT2(); } else { VMCNT0(); }  // U3,U4(t) done -> h1 resident
    BARRIER();
    __builtin_amdgcn_s_setprio(1);
    if (pf) STAGE_B(nb, t + 1, 0);
    LD_A(av3, rd0, boff, 2);
    LD_B(bv3, rd0, boff, 2);
    MFMA_CLUSTER(av2, bv2);
    __builtin_amdgcn_s_setprio(0);

    // ===== P3: MFMA s2 | ds_read s3 | stage U3(t+1) = A-h1
    BARRIER();
    __builtin_amdgcn_s_setprio(1);
    if (pf) STAGE_A(nb, t + 1, 1);
    LD_A(av4, rd1, boff, 3);
    LD_B(bv4, rd1, boff, 3);
    MFMA_CLUSTER(av3, bv3);
    __builtin_amdgcn_s_setprio(0);

    // ===== P4: MFMA s3 | ds_read s0(t+1) from nb | stage U4(t+1) = B-h1
    if (pf) { VMCNT2(); } else { VMCNT0(); }  // U1,U2(t+1) done -> h0 resident
    BARRIER();
    __builtin_amdgcn_s_setprio(1);
    if (pf) {
      STAGE_B(nb, t + 1, 1);
      LD_A(av1, rd0, nboff, 0);
      LD_B(bv1, rd0, nboff, 0);
    }
    MFMA_CLUSTER(av4, bv4);
    __builtin_amdgcn_s_setprio(0);
  }
#undef STAGE_A
#undef STAGE_B
#undef LD_A
#undef LD_B
#undef MFMA_CLUSTER

  // ---- epilogue: C = i32acc * sx[row] * sw[col]
  // 32x32 C/D map (m74/m101, dtype-independent m127/m128):
  //   col = lane&31, row = (reg&3) + 8*(reg>>2) + 4*(lane>>5)
  const int ec = lane & 31;
  const int rq = (lane >> 5) * 4;
#pragma unroll
  for (int f = 0; f < 4; ++f) {
    const long rb = m0 + wr * 128 + f * 32;
    float sxv[16];
#pragma unroll
    for (int r = 0; r < 16; ++r)
      sxv[r] = sx[rb + (r & 3) + 8 * (r >> 2) + rq];
#pragma unroll
    for (int g = 0; g < 2; ++g) {
      const long cb = n0 + wc * 64 + g * 32 + ec;
      const float swc = sw[cb];
#pragma unroll
      for (int r = 0; r < 16; ++r) {
        const long row = rb + (r & 3) + 8 * (r >> 2) + rq;
        C[row * OUT_F + cb] = (float)acc[f][g][r] * sxv[r] * swc;
      }
    }
  }
}

// ---------------------------------------------------------------------------
// Fallback (ws too small): slow but correct fp32 path.
// ---------------------------------------------------------------------------
__global__ __launch_bounds__(256) void fallback_kernel(
    const float* __restrict__ x, const int* __restrict__ bw,
    const float* __restrict__ scales, const float* __restrict__ vals,
    const int* __restrict__ cols, const int* __restrict__ rptr,
    float* __restrict__ out) {
  const int oc  = blockIdx.x * 64 + (threadIdx.x & 63);
  const int tok = blockIdx.y * 4 + (threadIdx.x >> 6);
  const float s = scales[oc];
  const int* bwr = bw + (size_t)oc * (IN_F / 2);
  const float* xr = x + (size_t)tok * IN_F;
  float acc = 0.f;
  for (int j = 0; j < IN_F / 2; ++j) {
    int p = bwr[j];
    int lo = p & 15;        lo = (lo >= 8) ? lo - 16 : lo;
    int hi = (p >> 4) & 15; hi = (hi >= 8) ? hi - 16 : hi;
    acc += ((float)lo * s) * xr[2 * j] + ((float)hi * s) * xr[2 * j + 1];
  }
  const int b = rptr[oc], e = rptr[oc + 1];
  for (int t = b; t < e; ++t) acc += vals[t] * xr[cols[t]];
  out[(size_t)tok * OUT_F + oc] = acc;
}

extern "C" void kernel_launch(void* const* d_in, const int* in_sizes, int n_in,
                              void* d_out, int out_size, void* d_ws, size_t ws_size,
                              hipStream_t stream) {
  const float* x      = (const float*)d_in[0];
  const int*   bw     = (const int*)d_in[1];
  const float* scales = (const float*)d_in[2];
  const float* vals   = (const float*)d_in[3];
  const int*   cols   = (const int*)d_in[4];
  const int*   rptr   = (const int*)d_in[5];
  float* out = (float*)d_out;

  // workspace: Wq 16MB | Xq 32MB | sw 16KB | sx 32KB
  const size_t wq_off = 0;
  const size_t xq_off = (size_t)OUT_F * IN_F;            // 16 MB
  const size_t sw_off = xq_off + (size_t)TOKENS * IN_F;  // 48 MB
  const size_t sx_off = sw_off + 65536;
  const size_t need   = sx_off + 65536;

  if (ws_size >= need) {
    signed char* Wq = (signed char*)d_ws + wq_off;
    signed char* Xq = (signed char*)d_ws + xq_off;
    float* sw = (float*)((char*)d_ws + sw_off);
    float* sx = (float*)((char*)d_ws + sx_off);
    prep_w_i8<<<OUT_F, 256, 0, stream>>>(bw, scales, vals, cols, rptr, Wq, sw);
    cvt_x_i8<<<TOKENS, 256, 0, stream>>>((const float4*)x, (int*)Xq, sx);
    gemm_i8<<<(TOKENS / BM) * (OUT_F / BN), 512, 0, stream>>>(
        (const unsigned char*)Xq, (const unsigned char*)Wq, sx, sw, out);
  } else {
    dim3 grid(OUT_F / 64, TOKENS / 4);
    fallback_kernel<<<grid, 256, 0, stream>>>(x, bw, scales, vals, cols, rptr, out);
  }
}

// Round 15
// 179.353 us; speedup vs baseline: 1.0929x; 1.0929x over previous
//
#include <hip/hip_runtime.h>
#include <hip/hip_bf16.h>

#define TOKENS 8192
#define IN_F   4096
#define OUT_F  4096

// GEMM geometry: 256x256 tile, K_STEP=128 (2 x K=64 MFMA steps), 8 waves
#define BM 256
#define BN 256
#define KSTEP 128
#define NT (IN_F / KSTEP)   // 32 K-tiles

typedef int   i32x4  __attribute__((ext_vector_type(4)));

#define BARRIER() asm volatile("s_barrier" ::: "memory")
#define VMCNT4()  asm volatile("s_waitcnt vmcnt(4)" ::: "memory")
#define VMCNT2()  asm volatile("s_waitcnt vmcnt(2)" ::: "memory")
#define VMCNT0()  asm volatile("s_waitcnt vmcnt(0)" ::: "memory")

__device__ __forceinline__ void gload_lds16(const void* g, void* l) {
  __builtin_amdgcn_global_load_lds(
      (const __attribute__((address_space(1))) void*)g,
      (__attribute__((address_space(3))) void*)l, 16, 0, 0);
}

__device__ __forceinline__ float blockmax256(float m, float* red) {
#pragma unroll
  for (int off = 32; off; off >>= 1)
    m = fmaxf(m, __shfl_xor(m, off, 64));
  if ((threadIdx.x & 63) == 0) red[threadIdx.x >> 6] = m;
  __syncthreads();
  return fmaxf(fmaxf(red[0], red[1]), fmaxf(red[2], red[3]));
}

__device__ __forceinline__ int pack4(const float* v, float inv) {
  unsigned w = 0;
#pragma unroll
  for (int b = 0; b < 4; ++b) {
    int q = __float2int_rn(fmaxf(fminf(v[b] * inv, 127.f), -127.f));
    w |= ((unsigned)(unsigned char)(signed char)q) << (8 * b);
  }
  return (int)w;
}

// ---------------------------------------------------------------------------
// Kernel 1 (fused prep): blocks [0, OUT_F) build W rows (dequant int4 + CSR
// -> per-row i8 + scale); blocks [OUT_F, OUT_F+TOKENS) quantize X tokens.
// Fusing removes one launch gap and lets both streams share the GPU
// (combined ~184 MB at streaming BW instead of two serialized passes).
// ---------------------------------------------------------------------------
__global__ __launch_bounds__(256) void prep_fused(
    const int* __restrict__ bw, const float* __restrict__ scales,
    const float* __restrict__ vals, const int* __restrict__ cols,
    const int* __restrict__ rptr, signed char* __restrict__ Wq,
    float* __restrict__ sw,
    const float4* __restrict__ x, int* __restrict__ xq,
    float* __restrict__ sx) {
  __shared__ float row[IN_F];
  __shared__ float red[4];
  const int tid = threadIdx.x;

  if (blockIdx.x < OUT_F) {
    // ---- W path (one block per output row) ----
    const int n = blockIdx.x;
    const float s = scales[n];
    const int* bwr = bw + (size_t)n * (IN_F / 2);
#pragma unroll
    for (int it = 0; it < (IN_F / 2) / 256; ++it) {
      int j = it * 256 + tid;
      int p = bwr[j];
      int lo = p & 15;        lo = (lo >= 8) ? lo - 16 : lo;
      int hi = (p >> 4) & 15; hi = (hi >= 8) ? hi - 16 : hi;
      row[2 * j]     = (float)lo * s;
      row[2 * j + 1] = (float)hi * s;
    }
    __syncthreads();
    const int b = rptr[n], e = rptr[n + 1];
    for (int t = b + tid; t < e; t += 256)
      atomicAdd(&row[cols[t]], vals[t]);
    __syncthreads();
    float m = 0.f;
#pragma unroll
    for (int it = 0; it < IN_F / 256; ++it)
      m = fmaxf(m, fabsf(row[it * 256 + tid]));
    const float mm  = fmaxf(blockmax256(m, red), 1e-30f);
    const float inv = 127.f / mm;
    int4 w;
    w.x = pack4(&row[tid * 16 + 0],  inv);
    w.y = pack4(&row[tid * 16 + 4],  inv);
    w.z = pack4(&row[tid * 16 + 8],  inv);
    w.w = pack4(&row[tid * 16 + 12], inv);
    *(int4*)(Wq + (size_t)n * IN_F + tid * 16) = w;
    if (tid == 0) sw[n] = mm / 127.f;
  } else {
    // ---- X path (one block per token) ----
    const int tok = blockIdx.x - OUT_F;
    const float4* xr = x + (size_t)tok * (IN_F / 4);
    float4 v[4];
    float m = 0.f;
#pragma unroll
    for (int j = 0; j < 4; ++j) {
      v[j] = xr[j * 256 + tid];
      m = fmaxf(m, fmaxf(fmaxf(fabsf(v[j].x), fabsf(v[j].y)),
                         fmaxf(fabsf(v[j].z), fabsf(v[j].w))));
    }
    const float mm  = fmaxf(blockmax256(m, red), 1e-30f);
    const float inv = 127.f / mm;
    int* xo = xq + (size_t)tok * (IN_F / 4);
#pragma unroll
    for (int j = 0; j < 4; ++j) {
      float vv[4] = {v[j].x, v[j].y, v[j].z, v[j].w};
      xo[j * 256 + tid] = pack4(vv, inv);
    }
    if (tid == 0) sx[tok] = mm / 127.f;
  }
}

// ---------------------------------------------------------------------------
// Kernel 2: i8 GEMM — R9 skeleton, byte-for-byte (verified 129.7 us, 0
// bank conflicts). 4 phases/K-tile, 1-phase fragment read-ahead, 2-3 phase
// stage lead with vmcnt(2) at P2/P4 entries; R7-geometry LDS (two 16KB
// halves, st_16x32 XOR swizzle; linear-dest staging w/ inverse-swizzled
// global source).
// ---------------------------------------------------------------------------
__global__ __launch_bounds__(512, 2) void gemm_i8(
    const unsigned char* __restrict__ A,   // [TOKENS][IN_F] i8
    const unsigned char* __restrict__ B,   // [OUT_F][IN_F] i8
    const float* __restrict__ sx,          // [TOKENS]
    const float* __restrict__ sw,          // [OUT_F]
    float* __restrict__ C) {               // [TOKENS][OUT_F] f32
  __shared__ __align__(16) char lds[131072];  // 2 buf x (A 32K + B 32K)

  const int nbn = OUT_F / BN;                  // 16
  const int cpx = ((TOKENS / BM) * nbn) >> 3;  // 64
  const int bid = blockIdx.x;
  const int swz = (bid & 7) * cpx + (bid >> 3);
  const int tm = swz / nbn, tn = swz % nbn;
  const long m0 = (long)tm * BM;
  const long n0 = (long)tn * BN;

  const int tid  = threadIdx.x;
  const int lane = tid & 63;
  const int wid  = tid >> 6;                // 0..7
  const int wr   = wid >> 2;                // 0..1
  const int wc   = wid & 3;                 // 0..3

  // ---- staging: linear LDS byte p -> logical (row, k-byte) (inverse swz)
  const int p0 = tid * 16;
  const int p1 = p0 + 8192;
  const int lin0 = p0 ^ (((p0 >> 9) & 1) << 5);
  const int lin1 = p1 ^ (((p1 >> 9) & 1) << 5);
  const int r0  = (((p0 >> 10) & 15) << 4) | ((lin0 >> 6) & 15);
  const int r1  = (((p1 >> 10) & 15) << 4) | ((lin1 >> 6) & 15);
  const int kb0 = lin0 & 63;
  const int kb1 = lin1 & 63;

  const unsigned char* Abase = A + m0 * IN_F;
  const unsigned char* Bbase = B + n0 * IN_F;

  // ---- reader lane offset (with XOR swizzle), R9-identical
  int laneoff = ((lane & 15) << 6) | ((lane >> 4) << 4);
  laneoff ^= ((laneoff >> 9) & 1) << 5;

#define STAGE_A(nb, kt, h)                                                     \
  do {                                                                         \
    gload_lds16(Abase + (size_t)r0 * IN_F + (kt) * 128 + (h) * 64 + kb0,       \
                lds + (nb) * 65536 + (h) * 16384 + p0);                        \
    gload_lds16(Abase + (size_t)r1 * IN_F + (kt) * 128 + (h) * 64 + kb1,       \
                lds + (nb) * 65536 + (h) * 16384 + p1);                        \
  } while (0)
#define STAGE_B(nb, kt, h)                                                     \
  do {                                                                         \
    gload_lds16(Bbase + (size_t)r0 * IN_F + (kt) * 128 + (h) * 64 + kb0,       \
                lds + (nb) * 65536 + 32768 + (h) * 16384 + p0);                \
    gload_lds16(Bbase + (size_t)r1 * IN_F + (kt) * 128 + (h) * 64 + kb1,       \
                lds + (nb) * 65536 + 32768 + (h) * 16384 + p1);                \
  } while (0)

  i32x4 acc[8][4];
#pragma unroll
  for (int i = 0; i < 8; ++i)
#pragma unroll
    for (int j = 0; j < 4; ++j) acc[i][j] = (i32x4)0;

  // fragment register sets (named, statically indexed — rule #20)
  i32x4 av1[4], av2[4], av3[4], av4[4], bv1[4], bv3[4];

  // ---- prologue: stage tile 0 into buf 0; preload s1(t0) after h0 resident
  STAGE_A(0, 0, 0);
  STAGE_B(0, 0, 0);
  STAGE_A(0, 0, 1);
  STAGE_B(0, 0, 1);
  VMCNT4();           // h0 of tile 0 resident (per-wave)
  BARRIER();
#pragma unroll
  for (int i = 0; i < 4; ++i)
    av1[i] = *(const i32x4*)(lds + (wr * 8 + i) * 1024 + laneoff);
#pragma unroll
  for (int j = 0; j < 4; ++j)
    bv1[j] = *(const i32x4*)(lds + 32768 + (wc * 4 + j) * 1024 + laneoff);

  for (int t = 0; t < NT; ++t) {
    const int b  = t & 1;
    const int nb = b ^ 1;
    const char* bufA  = lds + b * 65536;
    const char* bufB  = bufA + 32768;
    const char* nbufA = lds + nb * 65536;
    const char* nbufB = nbufA + 32768;
    const bool pf = (t + 1 < NT);

    // ===== P1: MFMA s1 (av1,bv1) | load av2 | stage A-h0(t+1)
    BARRIER();
    __builtin_amdgcn_s_setprio(1);
    if (pf) STAGE_A(nb, t + 1, 0);
#pragma unroll
    for (int i = 0; i < 4; ++i)
      av2[i] = *(const i32x4*)(bufA + (wr * 8 + 4 + i) * 1024 + laneoff);
#pragma unroll
    for (int i = 0; i < 4; ++i)
#pragma unroll
      for (int j = 0; j < 4; ++j)
        acc[i][j] = __builtin_amdgcn_mfma_i32_16x16x64_i8(av1[i], bv1[j], acc[i][j], 0, 0, 0);
    __builtin_amdgcn_s_setprio(0);

    // ===== P2: MFMA s2 (av2,bv1) | load av3,bv3 | stage B-h0(t+1)
    if (pf) { VMCNT2(); } else { VMCNT0(); }  // A-h1(t), B-h1(t) resident
    BARRIER();
    __builtin_amdgcn_s_setprio(1);
    if (pf) STAGE_B(nb, t + 1, 0);
#pragma unroll
    for (int i = 0; i < 4; ++i)
      av3[i] = *(const i32x4*)(bufA + 16384 + (wr * 8 + i) * 1024 + laneoff);
#pragma unroll
    for (int j = 0; j < 4; ++j)
      bv3[j] = *(const i32x4*)(bufB + 16384 + (wc * 4 + j) * 1024 + laneoff);
#pragma unroll
    for (int i = 0; i < 4; ++i)
#pragma unroll
      for (int j = 0; j < 4; ++j)
        acc[4 + i][j] = __builtin_amdgcn_mfma_i32_16x16x64_i8(av2[i], bv1[j], acc[4 + i][j], 0, 0, 0);
    __builtin_amdgcn_s_setprio(0);

    // ===== P3: MFMA s3 (av3,bv3) | load av4 | stage A-h1(t+1)
    BARRIER();
    __builtin_amdgcn_s_setprio(1);
    if (pf) STAGE_A(nb, t + 1, 1);
#pragma unroll
    for (int i = 0; i < 4; ++i)
      av4[i] = *(const i32x4*)(bufA + 16384 + (wr * 8 + 4 + i) * 1024 + laneoff);
#pragma unroll
    for (int i = 0; i < 4; ++i)
#pragma unroll
      for (int j = 0; j < 4; ++j)
        acc[i][j] = __builtin_amdgcn_mfma_i32_16x16x64_i8(av3[i], bv3[j], acc[i][j], 0, 0, 0);
    __builtin_amdgcn_s_setprio(0);

    // ===== P4: MFMA s4 (av4,bv3) | load s1(t+1) from buf nb | stage B-h1(t+1)
    if (pf) { VMCNT2(); } else { VMCNT0(); }  // A-h0(t+1), B-h0(t+1) resident
    BARRIER();
    __builtin_amdgcn_s_setprio(1);
    if (pf) {
      STAGE_B(nb, t + 1, 1);
#pragma unroll
      for (int i = 0; i < 4; ++i)
        av1[i] = *(const i32x4*)(nbufA + (wr * 8 + i) * 1024 + laneoff);
#pragma unroll
      for (int j = 0; j < 4; ++j)
        bv1[j] = *(const i32x4*)(nbufB + (wc * 4 + j) * 1024 + laneoff);
    }
#pragma unroll
    for (int i = 0; i < 4; ++i)
#pragma unroll
      for (int j = 0; j < 4; ++j)
        acc[4 + i][j] = __builtin_amdgcn_mfma_i32_16x16x64_i8(av4[i], bv3[j], acc[4 + i][j], 0, 0, 0);
    __builtin_amdgcn_s_setprio(0);
  }
#undef STAGE_A
#undef STAGE_B

  // ---- epilogue: C = i32acc * sx[row] * sw[col]
  const int er = (lane >> 4) * 4;
  const int ec = lane & 15;
#pragma unroll
  for (int i = 0; i < 8; ++i) {
    long rbase = m0 + wr * 128 + i * 16 + er;
    float sxq[4];
#pragma unroll
    for (int q = 0; q < 4; ++q) sxq[q] = sx[rbase + q];
#pragma unroll
    for (int j = 0; j < 4; ++j) {
      long cbase = n0 + wc * 64 + j * 16 + ec;
      const float swc = sw[cbase];
#pragma unroll
      for (int q = 0; q < 4; ++q)
        C[(rbase + q) * OUT_F + cbase] = (float)acc[i][j][q] * sxq[q] * swc;
    }
  }
}

// ---------------------------------------------------------------------------
// Fallback (ws too small): slow but correct fp32 path.
// ---------------------------------------------------------------------------
__global__ __launch_bounds__(256) void fallback_kernel(
    const float* __restrict__ x, const int* __restrict__ bw,
    const float* __restrict__ scales, const float* __restrict__ vals,
    const int* __restrict__ cols, const int* __restrict__ rptr,
    float* __restrict__ out) {
  const int oc  = blockIdx.x * 64 + (threadIdx.x & 63);
  const int tok = blockIdx.y * 4 + (threadIdx.x >> 6);
  const float s = scales[oc];
  const int* bwr = bw + (size_t)oc * (IN_F / 2);
  const float* xr = x + (size_t)tok * IN_F;
  float acc = 0.f;
  for (int j = 0; j < IN_F / 2; ++j) {
    int p = bwr[j];
    int lo = p & 15;        lo = (lo >= 8) ? lo - 16 : lo;
    int hi = (p >> 4) & 15; hi = (hi >= 8) ? hi - 16 : hi;
    acc += ((float)lo * s) * xr[2 * j] + ((float)hi * s) * xr[2 * j + 1];
  }
  const int b = rptr[oc], e = rptr[oc + 1];
  for (int t = b; t < e; ++t) acc += vals[t] * xr[cols[t]];
  out[(size_t)tok * OUT_F + oc] = acc;
}

extern "C" void kernel_launch(void* const* d_in, const int* in_sizes, int n_in,
                              void* d_out, int out_size, void* d_ws, size_t ws_size,
                              hipStream_t stream) {
  const float* x      = (const float*)d_in[0];
  const int*   bw     = (const int*)d_in[1];
  const float* scales = (const float*)d_in[2];
  const float* vals   = (const float*)d_in[3];
  const int*   cols   = (const int*)d_in[4];
  const int*   rptr   = (const int*)d_in[5];
  float* out = (float*)d_out;

  // workspace: Wq 16MB | Xq 32MB | sw 16KB | sx 32KB
  const size_t wq_off = 0;
  const size_t xq_off = (size_t)OUT_F * IN_F;            // 16 MB
  const size_t sw_off = xq_off + (size_t)TOKENS * IN_F;  // 48 MB
  const size_t sx_off = sw_off + 65536;
  const size_t need   = sx_off + 65536;

  if (ws_size >= need) {
    signed char* Wq = (signed char*)d_ws + wq_off;
    signed char* Xq = (signed char*)d_ws + xq_off;
    float* sw = (float*)((char*)d_ws + sw_off);
    float* sx = (float*)((char*)d_ws + sx_off);
    prep_fused<<<OUT_F + TOKENS, 256, 0, stream>>>(
        bw, scales, vals, cols, rptr, Wq, sw,
        (const float4*)x, (int*)Xq, sx);
    gemm_i8<<<(TOKENS / BM) * (OUT_F / BN), 512, 0, stream>>>(
        (const unsigned char*)Xq, (const unsigned char*)Wq, sx, sw, out);
  } else {
    dim3 grid(OUT_F / 64, TOKENS / 4);
    fallback_kernel<<<grid, 256, 0, stream>>>(x, bw, scales, vals, cols, rptr, out);
  }
}